// Round 2
// baseline (761.673 us; speedup 1.0000x reference)
//
#include <hip/hip_runtime.h>
#include <hip/hip_bf16.h>

// CRF-as-RNN mean-field on MI355X. B=2, L=21, C=3, H=W=96, N=9216, NITERS=5.
//
// w[n][m] = exp2(gs[m] + f_n . fs[m])  (log2e pre-scaled; row factor cancels
// under row normalization). Per iter: P[n][l] = sum_m w[n][m]*MQ[l][m] via
// bf16 MFMA 16x16x32. W is generated DIRECTLY INTO A-FRAGMENT REGISTERS
// (each thread computes w for its own fragment slots, packs with
// v_cvt_pk_bf16_f32); MQ B-fragments are read directly from global
// (L1/L2-resident, reused by all 144 n-blocks). B-row 21 is a constant 1.0
// synthesized in registers, so MFMA column 21 yields rowsum(W) for free.
// No LDS, no barriers: the tile loop is pure streaming and waves free-run.
// msg = P/P[21]; Q = softmax_l(-(E0+msg)); MQ = Mu@Q (bf16).

#define BB 2
#define LL 21
#define LP (LL + 1)   // Ppart rows: 21 msg cols + 1 rowsum col
#define NNPX 9216
#define NITERS 5
#define LOG2E 1.4426950408889634f

typedef __attribute__((ext_vector_type(8))) short short8;
typedef __attribute__((ext_vector_type(4))) float f32x4;
typedef __attribute__((ext_vector_type(4))) unsigned int u32x4;

// ---------------- prep: features + Q0 + MQ0(bf16) ----------------
__global__ __launch_bounds__(256) void k_prep(
        const float* __restrict__ E0, const float* __restrict__ Refs,
        const float* __restrict__ Mu,
        float4* __restrict__ FN, float4* __restrict__ FS,
        __hip_bfloat16* __restrict__ MQ) {
    __shared__ float muS[LL * LL];
    for (int i = threadIdx.x; i < LL * LL; i += 256) muS[i] = Mu[i];
    __syncthreads();

    int idx = blockIdx.x * 256 + threadIdx.x;      // b*N + n
    int b = idx / NNPX, n = idx % NNPX;

    const float* rb = Refs + (size_t)b * 3 * NNPX + n;
    float r0 = rb[0], r1 = rb[NNPX], r2 = rb[2 * NNPX];
    FN[idx] = make_float4(r0, r1, r2, 0.f);
    float g = -0.5f * (r0 * r0 + r1 * r1 + r2 * r2);
    FS[idx] = make_float4(g * LOG2E, r0 * LOG2E, r1 * LOG2E, r2 * LOG2E);

    const float* eb = E0 + (size_t)b * LL * NNPX + n;
    float x[LL];
    float mx = -1e30f;
    for (int l = 0; l < LL; ++l) { x[l] = -eb[(size_t)l * NNPX]; mx = fmaxf(mx, x[l]); }
    float s = 0.f;
    for (int l = 0; l < LL; ++l) { x[l] = __builtin_amdgcn_exp2f((x[l] - mx) * LOG2E); s += x[l]; }
    float rs = __builtin_amdgcn_rcpf(s);
    for (int l = 0; l < LL; ++l) x[l] *= rs;

    __hip_bfloat16* mq = MQ + (size_t)b * LL * NNPX + n;
    for (int k = 0; k < LL; ++k) {
        float a = 0.f;
        for (int l = 0; l < LL; ++l) a += muS[k * LL + l] * x[l];
        mq[(size_t)k * NNPX] = __float2bfloat16(a);
    }
}

// ---------------- accumulate via MFMA (msg + rowsum fused, LDS-free) ------
// grid (288, S): blockIdx.x = b*144 + n-tile (64 rows), blockIdx.y = m-split.
// m-tiles of 64; split s handles tiles s, s+S, ... of 144.
__global__ __launch_bounds__(256, 4) void k_accum(
        const float4* __restrict__ FS, const float4* __restrict__ FN,
        const __hip_bfloat16* __restrict__ MQbf, float* __restrict__ Ppart, int S) {
    int t = threadIdx.x;
    int rb = blockIdx.x;
    int s  = blockIdx.y;
    int b  = rb / 144;
    int n0 = (rb % 144) * 64;
    int wv = t >> 6, lane = t & 63;
    int lr  = lane & 15;          // fragment row (A) / col (B) index
    int kof = (lane >> 4) * 8;    // k-octet offset within 32-wide K half

    // A-row feature for this thread: n = n0 + wv*16 + lr
    float4 fn = FN[b * NNPX + n0 + wv * 16 + lr];

    f32x4 acc0 = {0.f, 0.f, 0.f, 0.f};   // C cols 0..15
    f32x4 acc1 = {0.f, 0.f, 0.f, 0.f};   // C cols 16..21 (+zero)

    const float4* fsb = FS + (size_t)b * NNPX;
    const __hip_bfloat16* mqb = MQbf + (size_t)b * LL * NNPX;

    // B-fragment acc1 half: row l2 = 16+lr. l2<21: load MQ; ==21: ones; else 0
    const int l2 = 16 + lr;
    short8 ones8;
    {
        u32x4 o = {0x3F803F80u, 0x3F803F80u, 0x3F803F80u, 0x3F803F80u};
        ones8 = __builtin_bit_cast(short8, o);
    }
    short8 zero8;
    {
        u32x4 z = {0u, 0u, 0u, 0u};
        zero8 = __builtin_bit_cast(short8, z);
    }

    for (int tile = s; tile < 144; tile += S) {
        int m0 = tile * 64;

        // ---- B fragments straight from global (L1/L2-resident) ----
        const __hip_bfloat16* r0 = mqb + (size_t)lr * NNPX + m0 + kof;
        short8 b00 = *(const short8*)(r0);
        short8 b01 = *(const short8*)(r0 + 32);
        short8 b10, b11;
        if (l2 < LL) {
            const __hip_bfloat16* r1 = mqb + (size_t)l2 * NNPX + m0 + kof;
            b10 = *(const short8*)(r1);
            b11 = *(const short8*)(r1 + 32);
        } else if (l2 == LL) {
            b10 = ones8; b11 = ones8;   // rowsum column
        } else {
            b10 = zero8; b11 = zero8;
        }

        // ---- A fragment: generate w for this thread's 16 k-slots ----
        // half 0: m = m0 + kof + j
        float w0[8];
        #pragma unroll
        for (int j = 0; j < 8; ++j) {
            float4 F = fsb[m0 + kof + j];
            float lg = F.x + fn.x * F.y;
            lg += fn.y * F.z;
            lg += fn.z * F.w;
            w0[j] = __builtin_amdgcn_exp2f(lg);
        }
        u32x4 ap0;
        #pragma unroll
        for (int j = 0; j < 4; ++j) {
            unsigned int p;
            asm("v_cvt_pk_bf16_f32 %0, %1, %2" : "=v"(p) : "v"(w0[2 * j]), "v"(w0[2 * j + 1]));
            ap0[j] = p;
        }
        short8 a0 = __builtin_bit_cast(short8, ap0);

        // half 1: m = m0 + 32 + kof + j
        float w1[8];
        #pragma unroll
        for (int j = 0; j < 8; ++j) {
            float4 F = fsb[m0 + 32 + kof + j];
            float lg = F.x + fn.x * F.y;
            lg += fn.y * F.z;
            lg += fn.z * F.w;
            w1[j] = __builtin_amdgcn_exp2f(lg);
        }
        u32x4 ap1;
        #pragma unroll
        for (int j = 0; j < 4; ++j) {
            unsigned int p;
            asm("v_cvt_pk_bf16_f32 %0, %1, %2" : "=v"(p) : "v"(w1[2 * j]), "v"(w1[2 * j + 1]));
            ap1[j] = p;
        }
        short8 a1 = __builtin_bit_cast(short8, ap1);

        acc0 = __builtin_amdgcn_mfma_f32_16x16x32_bf16(a0, b00, acc0, 0, 0, 0);
        acc0 = __builtin_amdgcn_mfma_f32_16x16x32_bf16(a1, b01, acc0, 0, 0, 0);
        acc1 = __builtin_amdgcn_mfma_f32_16x16x32_bf16(a0, b10, acc1, 0, 0, 0);
        acc1 = __builtin_amdgcn_mfma_f32_16x16x32_bf16(a1, b11, acc1, 0, 0, 0);
    }

    // epilogue: C layout col=lane&15, row=(lane>>4)*4+reg
    int col = lane & 15, qr = lane >> 4;
    float* pp = Ppart + ((size_t)(s * BB + b) * LP) * NNPX;
    for (int r = 0; r < 4; ++r) {
        int n = n0 + wv * 16 + qr * 4 + r;
        pp[(size_t)col * NNPX + n] = acc0[r];
        if (col < LP - 16) pp[(size_t)(16 + col) * NNPX + n] = acc1[r];
    }
}

// ---------------- reduce partials + softmax + Potts mix ----------------
template <bool LAST>
__global__ __launch_bounds__(256) void k_softmax(
        const float* __restrict__ E0, const float* __restrict__ Ppart,
        const float* __restrict__ Mu,
        __hip_bfloat16* __restrict__ MQ, float* __restrict__ Out, int S) {
    __shared__ float muS[LL * LL];
    for (int i = threadIdx.x; i < LL * LL; i += 256) muS[i] = Mu[i];
    __syncthreads();

    int idx = blockIdx.x * 256 + threadIdx.x;
    int b = idx / NNPX, n = idx % NNPX;

    float P[LP];
    for (int l = 0; l < LP; ++l) P[l] = 0.f;
    for (int s = 0; s < S; ++s) {
        const float* pp = Ppart + ((size_t)(s * BB + b) * LP) * NNPX + n;
        for (int l = 0; l < LP; ++l) P[l] += pp[(size_t)l * NNPX];
    }
    float rinv = __builtin_amdgcn_rcpf(P[LL]);   // rowsum from MFMA col 21

    const float* eb = E0 + (size_t)b * LL * NNPX + n;
    float mx = -1e30f;
    for (int l = 0; l < LL; ++l) {
        P[l] = -(eb[(size_t)l * NNPX] + P[l] * rinv);
        mx = fmaxf(mx, P[l]);
    }
    float ssum = 0.f;
    for (int l = 0; l < LL; ++l) { P[l] = __builtin_amdgcn_exp2f((P[l] - mx) * LOG2E); ssum += P[l]; }
    float rs = __builtin_amdgcn_rcpf(ssum);
    for (int l = 0; l < LL; ++l) P[l] *= rs;

    if (LAST) {
        float* ob = Out + (size_t)b * LL * NNPX + n;
        for (int l = 0; l < LL; ++l) ob[(size_t)l * NNPX] = P[l];
    } else {
        __hip_bfloat16* mq = MQ + (size_t)b * LL * NNPX + n;
        for (int k = 0; k < LL; ++k) {
            float a = 0.f;
            for (int l = 0; l < LL; ++l) a += muS[k * LL + l] * P[l];
            mq[(size_t)k * NNPX] = __float2bfloat16(a);
        }
    }
}

extern "C" void kernel_launch(void* const* d_in, const int* in_sizes, int n_in,
                              void* d_out, int out_size, void* d_ws, size_t ws_size,
                              hipStream_t stream) {
    const float* E0   = (const float*)d_in[0];
    const float* Refs = (const float*)d_in[1];
    const float* Mu   = (const float*)d_in[2];
    float* out = (float*)d_out;

    char* w = (char*)d_ws;
    size_t off = 0;
    auto alloc = [&](size_t bytes) {
        void* p = w + off;
        off += (bytes + 255) & ~(size_t)255;
        return p;
    };
    float4* FN     = (float4*)alloc((size_t)BB * NNPX * sizeof(float4));
    float4* FS     = (float4*)alloc((size_t)BB * NNPX * sizeof(float4));
    __hip_bfloat16* MQbf = (__hip_bfloat16*)alloc((size_t)BB * LL * NNPX * sizeof(__hip_bfloat16));

    // m-split S (divisor of 144, capped at 8) whose partial buffer fits in ws
    size_t per = (size_t)BB * LP * NNPX * sizeof(float);
    size_t avail = ws_size > off ? ws_size - off : 0;
    int Smax = (int)(avail / (per + 256));
    static const int divs[] = {8, 6, 4, 3, 2, 1};
    int S = 1;
    for (int i = 0; i < 6; ++i) if (divs[i] <= Smax) { S = divs[i]; break; }
    float* Ppart = (float*)alloc((size_t)S * per);

    k_prep<<<BB * NNPX / 256, 256, 0, stream>>>(E0, Refs, Mu, FN, FS, MQbf);
    for (int it = 0; it < NITERS; ++it) {
        k_accum<<<dim3(288, S), 256, 0, stream>>>(FS, FN, MQbf, Ppart, S);
        if (it == NITERS - 1)
            k_softmax<true><<<BB * NNPX / 256, 256, 0, stream>>>(E0, Ppart, Mu, MQbf, out, S);
        else
            k_softmax<false><<<BB * NNPX / 256, 256, 0, stream>>>(E0, Ppart, Mu, MQbf, out, S);
    }
}

// Round 3
// 398.117 us; speedup vs baseline: 1.9132x; 1.9132x over previous
//
#include <hip/hip_runtime.h>
#include <hip/hip_bf16.h>

// CRF-as-RNN mean-field on MI355X. B=2, L=21, C=3, H=W=96, N=9216, NITERS=5.
//
// w[n][m] = exp2(gs[m] + f_n . fs[m])  (log2e pre-scaled; row factor cancels
// under row normalization). Per iter: P[n][l] = sum_m w[n][m]*MQ[l][m] via
// bf16 MFMA 16x16x32. W generated on the fly into LDS (A-tile) with the
// R1 work mapping (each thread: 4 distinct FS loads -> 16 w; minimizes
// replicated FS delivery, which killed the LDS-free R2 variant). W and MQ
// tiles are DOUBLE-BUFFERED: one barrier per tile; tile t+1's global loads
// issue before tile t's MFMA, w-gen(t+1) fills the other buffer after.
// B-row 21 is constant 1.0 (in regs) so MFMA col 21 = rowsum(W) for free.
// msg = P/P[21]; Q = softmax_l(-(E0+msg)); MQ = Mu@Q (bf16).

#define BB 2
#define LL 21
#define LP (LL + 1)   // Ppart rows: 21 msg cols + 1 rowsum col
#define NNPX 9216
#define NITERS 5
#define LOG2E 1.4426950408889634f

typedef __attribute__((ext_vector_type(8))) short short8;
typedef __attribute__((ext_vector_type(4))) float f32x4;
typedef __attribute__((ext_vector_type(4))) unsigned int u32x4;

static __device__ inline unsigned int pk_bf16(float a, float b) {
    __hip_bfloat162 h = __float22bfloat162_rn(make_float2(a, b));
    unsigned int u;
    __builtin_memcpy(&u, &h, 4);
    return u;
}

// ---------------- prep: features + Q0 + MQ0(bf16) ----------------
__global__ __launch_bounds__(256) void k_prep(
        const float* __restrict__ E0, const float* __restrict__ Refs,
        const float* __restrict__ Mu,
        float4* __restrict__ FN, float4* __restrict__ FS,
        __hip_bfloat16* __restrict__ MQ) {
    __shared__ float muS[LL * LL];
    for (int i = threadIdx.x; i < LL * LL; i += 256) muS[i] = Mu[i];
    __syncthreads();

    int idx = blockIdx.x * 256 + threadIdx.x;      // b*N + n
    int b = idx / NNPX, n = idx % NNPX;

    const float* rb = Refs + (size_t)b * 3 * NNPX + n;
    float r0 = rb[0], r1 = rb[NNPX], r2 = rb[2 * NNPX];
    FN[idx] = make_float4(r0, r1, r2, 0.f);
    float g = -0.5f * (r0 * r0 + r1 * r1 + r2 * r2);
    FS[idx] = make_float4(g * LOG2E, r0 * LOG2E, r1 * LOG2E, r2 * LOG2E);

    const float* eb = E0 + (size_t)b * LL * NNPX + n;
    float x[LL];
    float mx = -1e30f;
    for (int l = 0; l < LL; ++l) { x[l] = -eb[(size_t)l * NNPX]; mx = fmaxf(mx, x[l]); }
    float s = 0.f;
    for (int l = 0; l < LL; ++l) { x[l] = __builtin_amdgcn_exp2f((x[l] - mx) * LOG2E); s += x[l]; }
    float rs = __builtin_amdgcn_rcpf(s);
    for (int l = 0; l < LL; ++l) x[l] *= rs;

    __hip_bfloat16* mq = MQ + (size_t)b * LL * NNPX + n;
    for (int k = 0; k < LL; ++k) {
        float a = 0.f;
        for (int l = 0; l < LL; ++l) a += muS[k * LL + l] * x[l];
        mq[(size_t)k * NNPX] = __float2bfloat16(a);
    }
}

// ---------------- accumulate via MFMA (msg + rowsum fused) ----------------
// grid (288, S): blockIdx.x = b*144 + n-tile (64 rows), blockIdx.y = s.
// Block handles CONTIGUOUS m-tiles [s*T, (s+1)*T), T = 144/S, tiles of 64.
__global__ __launch_bounds__(256, 4) void k_accum(
        const float4* __restrict__ FS, const float4* __restrict__ FN,
        const unsigned int* __restrict__ MQbf, float* __restrict__ Ppart, int S) {
    // double-buffered: W[2]: 64 n x 72 k bf16 (stride 72 = +8 pad);
    //                  M[2]: 21 l x 72 k bf16
    __shared__ __align__(16) unsigned short Wlds[2][64 * 72];
    __shared__ __align__(16) unsigned short Mlds[2][21 * 72];

    int t = threadIdx.x;
    int rb = blockIdx.x;
    int s  = blockIdx.y;
    int b  = rb / 144;
    int n0 = (rb % 144) * 64;
    int wv = t >> 6, lane = t & 63;
    int lr = lane & 15, g = lane >> 4;

    // w-gen mapping (block-wide): thread owns n = ng + 16*i (i<4), m-quad mq
    int mq = t & 15;
    int ng = t >> 4;
    float4 fnr[4];
    for (int i = 0; i < 4; ++i) fnr[i] = FN[b * NNPX + n0 + ng + 16 * i];

    const int T  = 144 / S;
    const int t0 = s * T;
    const float4* fsb = FS + (size_t)b * NNPX;
    const unsigned int* mqb = MQbf + (size_t)b * LL * (NNPX / 2);

    // MQ stage ownership: dwords idx = t + 256*r (r<3), idx < 21*32 = 672
    int sl0 = t >> 5, sm0 = t & 31;                     // idx = t
    int sl1 = (t + 256) >> 5, sm1 = (t + 256) & 31;     // idx = t+256
    int sl2 = (t + 512) >> 5, sm2 = (t + 512) & 31;     // idx = t+512 (<672 iff t<160)

    f32x4 acc0 = {0.f, 0.f, 0.f, 0.f};   // C cols 0..15
    f32x4 acc1 = {0.f, 0.f, 0.f, 0.f};   // C cols 16..21 (+zero)

    short8 ones8, zero8;
    {
        u32x4 o = {0x3F803F80u, 0x3F803F80u, 0x3F803F80u, 0x3F803F80u};
        ones8 = __builtin_bit_cast(short8, o);
        u32x4 z = {0u, 0u, 0u, 0u};
        zero8 = __builtin_bit_cast(short8, z);
    }

    float4 fsr[4];
    unsigned int mr0, mr1, mr2;

    // ---- tile-parameterized load / store-to-LDS steps ----
    auto LOADFS = [&](int tile) {
        int m0 = (t0 + tile) * 64;
        #pragma unroll
        for (int j = 0; j < 4; ++j) fsr[j] = fsb[m0 + 4 * mq + j];
    };
    auto LOADMQ = [&](int tile) {
        int mo0 = (t0 + tile) * 32;                      // dword offset of tile
        mr0 = mqb[(size_t)sl0 * (NNPX / 2) + mo0 + sm0];
        mr1 = mqb[(size_t)sl1 * (NNPX / 2) + mo0 + sm1];
        if (t < 160) mr2 = mqb[(size_t)sl2 * (NNPX / 2) + mo0 + sm2];
    };
    auto STORE = [&](int buf) {
        // MQ dwords
        ((unsigned int*)&Mlds[buf][sl0 * 72])[sm0] = mr0;
        ((unsigned int*)&Mlds[buf][sl1 * 72])[sm1] = mr1;
        if (t < 160) ((unsigned int*)&Mlds[buf][sl2 * 72])[sm2] = mr2;
        // w-gen: 4 n-rows x 4 m each
        #pragma unroll
        for (int i = 0; i < 4; ++i) {
            float4 f = fnr[i];
            float w0 = __builtin_amdgcn_exp2f(fsr[0].x + f.x * fsr[0].y + f.y * fsr[0].z + f.z * fsr[0].w);
            float w1 = __builtin_amdgcn_exp2f(fsr[1].x + f.x * fsr[1].y + f.y * fsr[1].z + f.z * fsr[1].w);
            float w2 = __builtin_amdgcn_exp2f(fsr[2].x + f.x * fsr[2].y + f.y * fsr[2].z + f.z * fsr[2].w);
            float w3 = __builtin_amdgcn_exp2f(fsr[3].x + f.x * fsr[3].y + f.y * fsr[3].z + f.z * fsr[3].w);
            uint2 pk;
            pk.x = pk_bf16(w0, w1);
            pk.y = pk_bf16(w2, w3);
            *(uint2*)&Wlds[buf][(ng + 16 * i) * 72 + 4 * mq] = pk;
        }
    };

    // ---- prologue: fill buffer 0 ----
    LOADFS(0);
    LOADMQ(0);
    STORE(0);
    __syncthreads();

    // ---- main loop: 1 barrier per tile ----
    int row = wv * 16 + lr;
    for (int tt = 0; tt < T; ++tt) {
        int cur = tt & 1;
        bool more = (tt + 1) < T;
        if (more) { LOADFS(tt + 1); LOADMQ(tt + 1); }

        short8 a0  = *(const short8*)&Wlds[cur][row * 72 + g * 8];
        short8 a1  = *(const short8*)&Wlds[cur][row * 72 + g * 8 + 32];
        short8 b00 = *(const short8*)&Mlds[cur][lr * 72 + g * 8];
        short8 b01 = *(const short8*)&Mlds[cur][lr * 72 + g * 8 + 32];
        short8 b10, b11;
        if (lr < 5) {
            b10 = *(const short8*)&Mlds[cur][(16 + lr) * 72 + g * 8];
            b11 = *(const short8*)&Mlds[cur][(16 + lr) * 72 + g * 8 + 32];
        } else if (lr == 5) {
            b10 = ones8; b11 = ones8;     // rowsum column (l = 21)
        } else {
            b10 = zero8; b11 = zero8;
        }
        acc0 = __builtin_amdgcn_mfma_f32_16x16x32_bf16(a0, b00, acc0, 0, 0, 0);
        acc0 = __builtin_amdgcn_mfma_f32_16x16x32_bf16(a1, b01, acc0, 0, 0, 0);
        acc1 = __builtin_amdgcn_mfma_f32_16x16x32_bf16(a0, b10, acc1, 0, 0, 0);
        acc1 = __builtin_amdgcn_mfma_f32_16x16x32_bf16(a1, b11, acc1, 0, 0, 0);

        if (more) STORE(cur ^ 1);
        __syncthreads();
    }

    // epilogue: C layout col=lane&15, row=(lane>>4)*4+reg
    int col = lane & 15, qr = lane >> 4;
    float* pp = Ppart + ((size_t)(s * BB + b) * LP) * NNPX;
    for (int r = 0; r < 4; ++r) {
        int n = n0 + wv * 16 + qr * 4 + r;
        pp[(size_t)col * NNPX + n] = acc0[r];
        if (col < LP - 16) pp[(size_t)(16 + col) * NNPX + n] = acc1[r];
    }
}

// ---------------- reduce partials + softmax + Potts mix ----------------
template <bool LAST>
__global__ __launch_bounds__(256) void k_softmax(
        const float* __restrict__ E0, const float* __restrict__ Ppart,
        const float* __restrict__ Mu,
        __hip_bfloat16* __restrict__ MQ, float* __restrict__ Out, int S) {
    __shared__ float muS[LL * LL];
    for (int i = threadIdx.x; i < LL * LL; i += 256) muS[i] = Mu[i];
    __syncthreads();

    int idx = blockIdx.x * 256 + threadIdx.x;
    int b = idx / NNPX, n = idx % NNPX;

    float P[LP];
    for (int l = 0; l < LP; ++l) P[l] = 0.f;
    for (int s = 0; s < S; ++s) {
        const float* pp = Ppart + ((size_t)(s * BB + b) * LP) * NNPX + n;
        for (int l = 0; l < LP; ++l) P[l] += pp[(size_t)l * NNPX];
    }
    float rinv = __builtin_amdgcn_rcpf(P[LL]);   // rowsum from MFMA col 21

    const float* eb = E0 + (size_t)b * LL * NNPX + n;
    float mx = -1e30f;
    for (int l = 0; l < LL; ++l) {
        P[l] = -(eb[(size_t)l * NNPX] + P[l] * rinv);
        mx = fmaxf(mx, P[l]);
    }
    float ssum = 0.f;
    for (int l = 0; l < LL; ++l) { P[l] = __builtin_amdgcn_exp2f((P[l] - mx) * LOG2E); ssum += P[l]; }
    float rs = __builtin_amdgcn_rcpf(ssum);
    for (int l = 0; l < LL; ++l) P[l] *= rs;

    if (LAST) {
        float* ob = Out + (size_t)b * LL * NNPX + n;
        for (int l = 0; l < LL; ++l) ob[(size_t)l * NNPX] = P[l];
    } else {
        __hip_bfloat16* mq = MQ + (size_t)b * LL * NNPX + n;
        for (int k = 0; k < LL; ++k) {
            float a = 0.f;
            for (int l = 0; l < LL; ++l) a += muS[k * LL + l] * P[l];
            mq[(size_t)k * NNPX] = __float2bfloat16(a);
        }
    }
}

extern "C" void kernel_launch(void* const* d_in, const int* in_sizes, int n_in,
                              void* d_out, int out_size, void* d_ws, size_t ws_size,
                              hipStream_t stream) {
    const float* E0   = (const float*)d_in[0];
    const float* Refs = (const float*)d_in[1];
    const float* Mu   = (const float*)d_in[2];
    float* out = (float*)d_out;

    char* w = (char*)d_ws;
    size_t off = 0;
    auto alloc = [&](size_t bytes) {
        void* p = w + off;
        off += (bytes + 255) & ~(size_t)255;
        return p;
    };
    float4* FN     = (float4*)alloc((size_t)BB * NNPX * sizeof(float4));
    float4* FS     = (float4*)alloc((size_t)BB * NNPX * sizeof(float4));
    __hip_bfloat16* MQbf = (__hip_bfloat16*)alloc((size_t)BB * LL * NNPX * sizeof(__hip_bfloat16));

    // m-split S (divisor of 144, capped at 8) whose partial buffer fits in ws
    size_t per = (size_t)BB * LP * NNPX * sizeof(float);
    size_t avail = ws_size > off ? ws_size - off : 0;
    int Smax = (int)(avail / (per + 256));
    static const int divs[] = {8, 6, 4, 3, 2, 1};
    int S = 1;
    for (int i = 0; i < 6; ++i) if (divs[i] <= Smax) { S = divs[i]; break; }
    float* Ppart = (float*)alloc((size_t)S * per);

    k_prep<<<BB * NNPX / 256, 256, 0, stream>>>(E0, Refs, Mu, FN, FS, MQbf);
    for (int it = 0; it < NITERS; ++it) {
        k_accum<<<dim3(288, S), 256, 0, stream>>>(FS, FN, (const unsigned int*)MQbf, Ppart, S);
        if (it == NITERS - 1)
            k_softmax<true><<<BB * NNPX / 256, 256, 0, stream>>>(E0, Ppart, Mu, MQbf, out, S);
        else
            k_softmax<false><<<BB * NNPX / 256, 256, 0, stream>>>(E0, Ppart, Mu, MQbf, out, S);
    }
}